// Round 5
// baseline (13893.413 us; speedup 1.0000x reference)
//
#include <hip/hip_runtime.h>
#include <math.h>

#define TT 64      // timesteps per x/out tile staged in LDS
#define XS 68      // padded LDS row stride (floats)

// ---- AGPR weight residency ----
// Store: value lives in an AGPR (def is "=a" asm; cannot be remat'd, AGPR
// spill is last-resort). Read: explicit v_accvgpr_read each use, volatile so
// it cannot be hoisted out of the timestep loop (hoisting would re-create
// 128 long-lived VGPR values -> the exact spill problem we're fixing).
__device__ __forceinline__ void awrite(float& a, float v) {
    asm volatile("v_accvgpr_write_b32 %0, %1" : "=a"(a) : "v"(v));
}
__device__ __forceinline__ float aread(const float& a) {
    float t;
    asm volatile("v_accvgpr_read_b32 %0, %1" : "=v"(t) : "a"(a));
    return t;
}

__device__ __forceinline__ float rcp_(float x) { return __builtin_amdgcn_rcpf(x); }
__device__ __forceinline__ float sigm(float v) { return rcp_(1.0f + __expf(-v)); }
__device__ __forceinline__ float tanh_(float v) {
    float av = fabsf(v);
    float e  = __expf(-2.0f * av);
    float r  = (1.0f - e) * rcp_(1.0f + e);
    return copysignf(r, v);
}

// One block per batch element. 512 threads:
//   tid 0..255   = layer 0, gate j = tid
//   tid 256..511 = layer 1, gate j = tid-256
// Layers SKEWED: at iteration n, layer0 does timestep n, layer1 does n-1.
// 2 barriers per iteration; h vectors double-buffered in LDS.
// Weights: 128 floats per thread held in AGPRs (unified file, no MFMA user).
__global__ __launch_bounds__(512) void lstm2_skew_agpr(
    const float* __restrict__ x,      // [128][64][4096]
    const float* __restrict__ wih0,   // [256][64]
    const float* __restrict__ whh0,   // [256][64]
    const float* __restrict__ b0,     // [256]
    const float* __restrict__ wih1,   // [256][64]
    const float* __restrict__ whh1,   // [256][64]
    const float* __restrict__ b1,     // [256]
    float* __restrict__ out)          // [128][64][4096]
{
    const int b   = blockIdx.x;
    const int tid = threadIdx.x;
    const int layer = tid >> 8;       // wave-uniform (waves 0-3 = L0, 4-7 = L1)
    const int j   = tid & 255;

    __shared__ float xt[TT * XS];     // xt[tl][c] transposed x tile
    __shared__ float ot[64 * XS];     // ot[h][tl] output staging
    __shared__ float h0buf[2][64];
    __shared__ float h1buf[2][64];
    __shared__ float g0[256];
    __shared__ float g1[256];

    // Per-thread weights: one gate row of one layer (128 floats) -> AGPRs.
    float wax[64], wah[64];
    {
        const float* wxp = (layer == 0 ? wih0 : wih1) + j * 64;
        const float* whp = (layer == 0 ? whh0 : whh1) + j * 64;
#pragma unroll
        for (int i = 0; i < 16; ++i) {
            float4 v = ((const float4*)wxp)[i];
            awrite(wax[4 * i + 0], v.x);
            awrite(wax[4 * i + 1], v.y);
            awrite(wax[4 * i + 2], v.z);
            awrite(wax[4 * i + 3], v.w);
        }
#pragma unroll
        for (int i = 0; i < 16; ++i) {
            float4 v = ((const float4*)whp)[i];
            awrite(wah[4 * i + 0], v.x);
            awrite(wah[4 * i + 1], v.y);
            awrite(wah[4 * i + 2], v.z);
            awrite(wah[4 * i + 3], v.w);
        }
    }
    const float bias = (layer == 0 ? b0 : b1)[j];
    const bool tanh_gate = (j >= 128) && (j < 192);  // wave-uniform

    float cst = 0.0f;   // cell state: tid<64 holds c0, tid 256..319 holds c1

    if (tid < 64) {
        h0buf[0][tid] = 0.f; h0buf[1][tid] = 0.f;
        h1buf[0][tid] = 0.f; h1buf[1][tid] = 0.f;
    }

    const float* xb = x   + (size_t)b * 64 * 4096;
    float*       ob = out + (size_t)b * 64 * 4096;

    for (int n = 0; n <= 4096; ++n) {
        // ---- stage next x tile (every 64 iters); barrier covers h-init at n=0 ----
        if ((n & 63) == 0 && n < 4096) {
            for (int idx = tid; idx < 64 * 16; idx += 512) {
                int c = idx >> 4;      // channel
                int q = idx & 15;      // float4 index along t
                float4 v = *(const float4*)(xb + (size_t)c * 4096 + n + 4 * q);
                xt[(4 * q + 0) * XS + c] = v.x;
                xt[(4 * q + 1) * XS + c] = v.y;
                xt[(4 * q + 2) * XS + c] = v.z;
                xt[(4 * q + 3) * XS + c] = v.w;
            }
            __syncthreads();
        }

        // ---- phase A: both layers' gate GEMVs concurrently ----
        {
            const float4* av;
            const float4* hv;
            bool active;
            if (layer == 0) {
                active = (n < 4096);
                av = (const float4*)(xt + (n & 63) * XS);
                hv = (const float4*)(h0buf[n & 1]);
            } else {
                active = (n >= 1);
                av = (const float4*)(h0buf[n & 1]);   // input = h0[n-1]
                hv = (const float4*)(h1buf[n & 1]);   // recurrent h1[n-2]
            }
            if (active) {
                float a0=0,a1=0,a2=0,a3=0,c0_=0,c1_=0,c2_=0,c3_=0;
#pragma unroll
                for (int i = 0; i < 16; ++i) {
                    float4 v = av[i];
                    a0 += aread(wax[4 * i + 0]) * v.x;
                    a1 += aread(wax[4 * i + 1]) * v.y;
                    a2 += aread(wax[4 * i + 2]) * v.z;
                    a3 += aread(wax[4 * i + 3]) * v.w;
                }
#pragma unroll
                for (int i = 0; i < 16; ++i) {
                    float4 v = hv[i];
                    c0_ += aread(wah[4 * i + 0]) * v.x;
                    c1_ += aread(wah[4 * i + 1]) * v.y;
                    c2_ += aread(wah[4 * i + 2]) * v.z;
                    c3_ += aread(wah[4 * i + 3]) * v.w;
                }
                float acc = ((a0 + a1) + (a2 + a3)) + ((c0_ + c1_) + (c2_ + c3_)) + bias;
                float g = tanh_gate ? tanh_(acc) : sigm(acc);
                if (layer == 0) g0[j] = g; else g1[j] = g;
            }
        }
        __syncthreads();

        // ---- phase B: cell/hidden updates, both layers in parallel waves ----
        if (tid < 64) {                       // layer 0 update (wave 0)
            if (n < 4096) {
                float i_ = g0[tid];
                float f_ = g0[tid + 64];
                float gg = g0[tid + 128];
                float o_ = g0[tid + 192];
                cst = f_ * cst + i_ * gg;
                h0buf[(n + 1) & 1][tid] = o_ * tanh_(cst);
            }
        } else if (tid >= 256 && tid < 320) { // layer 1 update (wave 4)
            if (n >= 1) {
                int k = tid - 256;
                float i_ = g1[k];
                float f_ = g1[k + 64];
                float gg = g1[k + 128];
                float o_ = g1[k + 192];
                cst = f_ * cst + i_ * gg;
                float h = o_ * tanh_(cst);
                h1buf[(n + 1) & 1][k] = h;
                ot[k * XS + ((n - 1) & 63)] = h;
            }
        }
        __syncthreads();

        // ---- flush output tile every 64 iters (t1 range [n-64, n-1]) ----
        if (n > 0 && (n & 63) == 0) {
            int t0f = n - 64;
            for (int idx = tid; idx < 64 * 16; idx += 512) {
                int r = idx >> 4;
                int q = idx & 15;
                float4 v = *(const float4*)(ot + r * XS + 4 * q);
                *(float4*)(ob + (size_t)r * 4096 + t0f + 4 * q) = v;
            }
            // next write to ot happens after next iter's barriers
        }
    }
}

extern "C" void kernel_launch(void* const* d_in, const int* in_sizes, int n_in,
                              void* d_out, int out_size, void* d_ws, size_t ws_size,
                              hipStream_t stream) {
    const float* x    = (const float*)d_in[0];
    const float* wih0 = (const float*)d_in[1];
    const float* whh0 = (const float*)d_in[2];
    const float* b0   = (const float*)d_in[3];
    const float* wih1 = (const float*)d_in[4];
    const float* whh1 = (const float*)d_in[5];
    const float* b1   = (const float*)d_in[6];
    float* out = (float*)d_out;

    lstm2_skew_agpr<<<128, 512, 0, stream>>>(x, wih0, whh0, b0, wih1, whh1, b1, out);
}

// Round 7
// 3165.287 us; speedup vs baseline: 4.3893x; 4.3893x over previous
//
#include <hip/hip_runtime.h>
#include <math.h>

#define SEQ 4096
#define PIN4(v) asm volatile("" : "+v"(v.x), "+v"(v.y), "+v"(v.z), "+v"(v.w))

__device__ __forceinline__ float rcp_(float x) { return __builtin_amdgcn_rcpf(x); }
__device__ __forceinline__ float sigm(float v) { return rcp_(1.0f + __expf(-v)); }
__device__ __forceinline__ float tanh_(float v) {
    float av = fabsf(v);
    float e  = __expf(-2.0f * av);
    float r  = (1.0f - e) * rcp_(1.0f + e);
    return copysignf(r, v);
}

__device__ __forceinline__ float dot64(const float4* __restrict__ w, const float4* op) {
    float a0 = 0.f, a1 = 0.f, a2 = 0.f, a3 = 0.f;
#pragma unroll
    for (int i = 0; i < 16; ++i) {
        float4 v = op[i];
        a0 += w[i].x * v.x; a1 += w[i].y * v.y;
        a2 += w[i].z * v.z; a3 += w[i].w * v.w;
    }
    return (a0 + a1) + (a2 + a3);
}

__global__ void zero_flags(int* f, int n) {
    int i = blockIdx.x * blockDim.x + threadIdx.x;
    if (i < n) f[i] = 0;
}

// 256 blocks: block 2b = layer0 of batch b (producer), 2b+1 = layer1 (consumer).
// Producer streams h0 through d_out in 32-step tiles + release flags in d_ws;
// consumer acquires, stages tile to LDS, overwrites the same d_out cells with h1.
// 512 threads: tid = j + 256*half; half0 = W_ih row j, half1 = W_hh row j.
// 64 weight floats/thread -> low register pressure, weights stay resident.
__global__ __launch_bounds__(512, 2) void lstm2_split(
    const float* __restrict__ x,      // [128][64][4096]
    const float* __restrict__ wih0, const float* __restrict__ whh0,
    const float* __restrict__ b0,
    const float* __restrict__ wih1, const float* __restrict__ whh1,
    const float* __restrict__ b1,
    float* out,                       // h0 stream, then overwritten with h1
    int* flags)                       // [128][128] tile flags
{
    const int bid  = blockIdx.x;
    const int role = bid & 1;         // 0 = layer0 producer, 1 = layer1 consumer
    const int b    = bid >> 1;
    const int tid  = threadIdx.x;
    const int half = tid >> 8;        // wave-uniform
    const int j    = tid & 255;

    __shared__ float opbuf[64 * 68];            // producer: x tile [64t][64c]; consumer: h0 tile [32t][64c]
    __shared__ float stg[64 * 37];              // producer: h0 stage [32t][64u] (stride 68); consumer: h1 stage [64u][32t] (stride 37)
    __shared__ __align__(16) float hbuf[2][64]; // recurrent h (h0 or h1), double-buffered
    __shared__ float partial[512];

    const float* Wsel = (role == 0) ? (half == 0 ? wih0 : whh0)
                                    : (half == 0 ? wih1 : whh1);
    float4 w[16];
    {
        const float4* wp = (const float4*)(Wsel + (size_t)j * 64);
#pragma unroll
        for (int i = 0; i < 16; ++i) w[i] = wp[i];
#pragma unroll
        for (int i = 0; i < 16; ++i) PIN4(w[i]);
    }

    float bi = 0.f, bf = 0.f, bg = 0.f, bo = 0.f;
    if (tid < 64) {
        const float* bb = role ? b1 : b0;
        bi = bb[tid]; bf = bb[tid + 64]; bg = bb[tid + 128]; bo = bb[tid + 192];
        hbuf[0][tid] = 0.f; hbuf[1][tid] = 0.f;
    }

    const float* xb  = x   + (size_t)b * 64 * SEQ;
    float*       ob  = out + (size_t)b * 64 * SEQ;
    int*         flg = flags + b * 128;

    float cst = 0.f;

    if (role == 0) {
        // ================= producer: layer 0 =================
        for (int n = 0; n < SEQ; ++n) {
            if ((n & 63) == 0) {
                // stage x tile [n, n+63], transposed to opbuf[t][c]
                for (int idx = tid; idx < 64 * 16; idx += 512) {
                    int c = idx >> 4, q = idx & 15;
                    float4 v = *(const float4*)(xb + (size_t)c * SEQ + n + 4 * q);
                    opbuf[(4 * q + 0) * 68 + c] = v.x;
                    opbuf[(4 * q + 1) * 68 + c] = v.y;
                    opbuf[(4 * q + 2) * 68 + c] = v.z;
                    opbuf[(4 * q + 3) * 68 + c] = v.w;
                }
                __syncthreads();
            }
            const float4* op = (half == 0)
                ? (const float4*)(opbuf + (n & 63) * 68)
                : (const float4*)(hbuf[n & 1]);
            partial[tid] = dot64(w, op);
            __syncthreads();
            if (tid < 64) {
                float pi = partial[tid]       + partial[tid + 256] + bi;
                float pf = partial[tid + 64]  + partial[tid + 320] + bf;
                float pg = partial[tid + 128] + partial[tid + 384] + bg;
                float po = partial[tid + 192] + partial[tid + 448] + bo;
                float ii = sigm(pi), ff = sigm(pf), gg = tanh_(pg), oo = sigm(po);
                cst = ff * cst + ii * gg;
                float h = oo * tanh_(cst);
                hbuf[(n + 1) & 1][tid] = h;
                stg[(n & 31) * 68 + tid] = h;
            }
            __syncthreads();
            if ((n & 31) == 31) {
                // flush h0 tile to d_out[b][c][t0..t0+31]
                int t0 = n - 31;
                int c = tid >> 3, q = tid & 7;
                float4 v;
                v.x = stg[(4 * q + 0) * 68 + c];
                v.y = stg[(4 * q + 1) * 68 + c];
                v.z = stg[(4 * q + 2) * 68 + c];
                v.w = stg[(4 * q + 3) * 68 + c];
                *(float4*)(ob + (size_t)c * SEQ + t0 + 4 * q) = v;
                __syncthreads();          // all tile writes done
                if (tid == 0) {
                    __threadfence();      // device-scope visibility
                    __hip_atomic_store(&flg[n >> 5], 1, __ATOMIC_RELEASE,
                                       __HIP_MEMORY_SCOPE_AGENT);
                }
            }
        }
    } else {
        // ================= consumer: layer 1 =================
        for (int n = 0; n < SEQ; ++n) {
            if ((n & 31) == 0) {
                if (tid == 0) {
                    while (__hip_atomic_load(&flg[n >> 5], __ATOMIC_ACQUIRE,
                                             __HIP_MEMORY_SCOPE_AGENT) == 0)
                        __builtin_amdgcn_s_sleep(8);
                }
                __syncthreads();
                // stage h0 tile [n, n+31] from d_out, transposed to opbuf[t][c]
                {
                    int c = tid >> 3, q = tid & 7;
                    float4 v = *(const float4*)(ob + (size_t)c * SEQ + n + 4 * q);
                    opbuf[(4 * q + 0) * 68 + c] = v.x;
                    opbuf[(4 * q + 1) * 68 + c] = v.y;
                    opbuf[(4 * q + 2) * 68 + c] = v.z;
                    opbuf[(4 * q + 3) * 68 + c] = v.w;
                }
                __syncthreads();
            }
            const float4* op = (half == 0)
                ? (const float4*)(opbuf + (n & 31) * 68)
                : (const float4*)(hbuf[n & 1]);
            partial[tid] = dot64(w, op);
            __syncthreads();
            if (tid < 64) {
                float pi = partial[tid]       + partial[tid + 256] + bi;
                float pf = partial[tid + 64]  + partial[tid + 320] + bf;
                float pg = partial[tid + 128] + partial[tid + 384] + bg;
                float po = partial[tid + 192] + partial[tid + 448] + bo;
                float ii = sigm(pi), ff = sigm(pf), gg = tanh_(pg), oo = sigm(po);
                cst = ff * cst + ii * gg;
                float h = oo * tanh_(cst);
                hbuf[(n + 1) & 1][tid] = h;
                stg[tid * 37 + (n & 31)] = h;
            }
            __syncthreads();
            if ((n & 31) == 31) {
                // overwrite d_out tile with h1
                int t0 = n - 31;
                int c = tid >> 3, q = tid & 7;
                float4 v;
                v.x = stg[c * 37 + 4 * q + 0];
                v.y = stg[c * 37 + 4 * q + 1];
                v.z = stg[c * 37 + 4 * q + 2];
                v.w = stg[c * 37 + 4 * q + 3];
                *(float4*)(ob + (size_t)c * SEQ + t0 + 4 * q) = v;
                // no barrier needed: stg isn't rewritten until after next partial-sync
            }
        }
    }
}

extern "C" void kernel_launch(void* const* d_in, const int* in_sizes, int n_in,
                              void* d_out, int out_size, void* d_ws, size_t ws_size,
                              hipStream_t stream) {
    const float* x    = (const float*)d_in[0];
    const float* wih0 = (const float*)d_in[1];
    const float* whh0 = (const float*)d_in[2];
    const float* b0   = (const float*)d_in[3];
    const float* wih1 = (const float*)d_in[4];
    const float* whh1 = (const float*)d_in[5];
    const float* b1   = (const float*)d_in[6];
    float* out  = (float*)d_out;
    int*   flags = (int*)d_ws;           // 128 batches x 128 tiles

    zero_flags<<<64, 256, 0, stream>>>(flags, 128 * 128);
    lstm2_split<<<256, 512, 0, stream>>>(x, wih0, whh0, b0, wih1, whh1, b1,
                                         out, flags);
}

// Round 8
// 2381.934 us; speedup vs baseline: 5.8328x; 1.3289x over previous
//
#include <hip/hip_runtime.h>
#include <math.h>

#define SEQ 4096
#define XST 72   // f16 LDS row stride (144 B, 16B-aligned)
#define PIN4(v) asm volatile("" : "+v"(v.x), "+v"(v.y), "+v"(v.z), "+v"(v.w))

typedef _Float16 half2_t __attribute__((ext_vector_type(2)));
typedef _Float16 half8_t __attribute__((ext_vector_type(8)));
union H8 { half8_t h; half2_t h2[4]; float4 f4; };

__device__ __forceinline__ float dot2(half2_t a, half2_t b, float c) {
#if __has_builtin(__builtin_amdgcn_fdot2)
    return __builtin_amdgcn_fdot2(a, b, c, false);
#else
    return c + (float)a[0] * (float)b[0] + (float)a[1] * (float)b[1];
#endif
}

__device__ __forceinline__ float rcp_(float x) { return __builtin_amdgcn_rcpf(x); }
__device__ __forceinline__ float sigm(float v) { return rcp_(1.0f + __expf(-v)); }
__device__ __forceinline__ float tanh_(float v) {
    float av = fabsf(v);
    float e  = __expf(-2.0f * av);
    float r  = (1.0f - e) * rcp_(1.0f + e);
    return copysignf(r, v);
}

__global__ void zero_flags(int* f, int n) {
    int i = blockIdx.x * blockDim.x + threadIdx.x;
    if (i < n) f[i] = 0;
}

// R6 structure (layer-split producer/consumer, 256 blocks x 512 threads),
// GEMV in f16: weights as 32 half2/thread (PIN'd), operands staged as f16 in
// LDS, fdot2 with f32 accumulate. c/h/update/output/handoff all stay f32.
__global__ __launch_bounds__(512, 2) void lstm2_split_f16(
    const float* __restrict__ x,
    const float* __restrict__ wih0, const float* __restrict__ whh0,
    const float* __restrict__ b0,
    const float* __restrict__ wih1, const float* __restrict__ whh1,
    const float* __restrict__ b1,
    float* out,                       // h0 stream, then overwritten with h1
    int* flags)                       // [128][128] tile flags
{
    const int bid  = blockIdx.x;
    const int role = bid & 1;         // 0 = layer0 producer, 1 = layer1 consumer
    const int b    = bid >> 1;
    const int tid  = threadIdx.x;
    const int half = tid >> 8;        // wave-uniform
    const int j    = tid & 255;

    __shared__ _Float16 opb16[64 * XST];          // producer: x tile [64t][64c]; consumer: h0 tile [32t][64c]
    __shared__ float stg[64 * 37];                // h staging for global flush (f32)
    __shared__ __align__(16) _Float16 hbuf2[2][64]; // recurrent h (f16 for GEMV)
    __shared__ float partial[512];

    const float* Wsel = (role == 0) ? (half == 0 ? wih0 : whh0)
                                    : (half == 0 ? wih1 : whh1);
    // 64 f16 weights per thread = 8 x H8 = 32 VGPRs
    H8 w[8];
    {
        const float4* wp = (const float4*)(Wsel + (size_t)j * 64);
#pragma unroll
        for (int i = 0; i < 8; ++i) {
            float4 a = wp[2 * i], c = wp[2 * i + 1];
            w[i].h[0] = (_Float16)a.x; w[i].h[1] = (_Float16)a.y;
            w[i].h[2] = (_Float16)a.z; w[i].h[3] = (_Float16)a.w;
            w[i].h[4] = (_Float16)c.x; w[i].h[5] = (_Float16)c.y;
            w[i].h[6] = (_Float16)c.z; w[i].h[7] = (_Float16)c.w;
        }
#pragma unroll
        for (int i = 0; i < 8; ++i) PIN4(w[i].f4);
    }

    float bi = 0.f, bf = 0.f, bg = 0.f, bo = 0.f;
    if (tid < 64) {
        const float* bb = role ? b1 : b0;
        bi = bb[tid]; bf = bb[tid + 64]; bg = bb[tid + 128]; bo = bb[tid + 192];
        hbuf2[0][tid] = (_Float16)0.f; hbuf2[1][tid] = (_Float16)0.f;
    }

    const float* xb  = x   + (size_t)b * 64 * SEQ;
    float*       ob  = out + (size_t)b * 64 * SEQ;
    int*         flg = flags + b * 128;

    float cst = 0.f;

    if (role == 0) {
        // ================= producer: layer 0 =================
        for (int n = 0; n < SEQ; ++n) {
            if ((n & 63) == 0) {
                // stage x tile [n, n+63] transposed -> opb16[t][c], f32->f16
                for (int idx = tid; idx < 64 * 16; idx += 512) {
                    int c = idx >> 4, q = idx & 15;
                    float4 v = *(const float4*)(xb + (size_t)c * SEQ + n + 4 * q);
                    opb16[(4 * q + 0) * XST + c] = (_Float16)v.x;
                    opb16[(4 * q + 1) * XST + c] = (_Float16)v.y;
                    opb16[(4 * q + 2) * XST + c] = (_Float16)v.z;
                    opb16[(4 * q + 3) * XST + c] = (_Float16)v.w;
                }
                __syncthreads();
            }
            {
                const float4* op4 = (half == 0)
                    ? (const float4*)(opb16 + (n & 63) * XST)
                    : (const float4*)(hbuf2[n & 1]);
                float a0 = 0.f, a1 = 0.f, a2 = 0.f, a3 = 0.f;
#pragma unroll
                for (int i = 0; i < 8; ++i) {
                    H8 o; o.f4 = op4[i];
                    a0 = dot2(w[i].h2[0], o.h2[0], a0);
                    a1 = dot2(w[i].h2[1], o.h2[1], a1);
                    a2 = dot2(w[i].h2[2], o.h2[2], a2);
                    a3 = dot2(w[i].h2[3], o.h2[3], a3);
                }
                partial[tid] = (a0 + a1) + (a2 + a3);
            }
            __syncthreads();
            if (tid < 64) {
                float pi = partial[tid]       + partial[tid + 256] + bi;
                float pf = partial[tid + 64]  + partial[tid + 320] + bf;
                float pg = partial[tid + 128] + partial[tid + 384] + bg;
                float po = partial[tid + 192] + partial[tid + 448] + bo;
                float ii = sigm(pi), ff = sigm(pf), gg = tanh_(pg), oo = sigm(po);
                cst = ff * cst + ii * gg;
                float h = oo * tanh_(cst);
                hbuf2[(n + 1) & 1][tid] = (_Float16)h;
                stg[(n & 31) * 68 + tid] = h;
            }
            __syncthreads();
            if ((n & 31) == 31) {
                // flush h0 tile (f32) to d_out[b][c][t0..t0+31]
                int t0 = n - 31;
                int c = tid >> 3, q = tid & 7;
                float4 v;
                v.x = stg[(4 * q + 0) * 68 + c];
                v.y = stg[(4 * q + 1) * 68 + c];
                v.z = stg[(4 * q + 2) * 68 + c];
                v.w = stg[(4 * q + 3) * 68 + c];
                *(float4*)(ob + (size_t)c * SEQ + t0 + 4 * q) = v;
                __syncthreads();
                if (tid == 0) {
                    __threadfence();
                    __hip_atomic_store(&flg[n >> 5], 1, __ATOMIC_RELEASE,
                                       __HIP_MEMORY_SCOPE_AGENT);
                }
            }
        }
    } else {
        // ================= consumer: layer 1 =================
        for (int n = 0; n < SEQ; ++n) {
            if ((n & 31) == 0) {
                if (tid == 0) {
                    while (__hip_atomic_load(&flg[n >> 5], __ATOMIC_ACQUIRE,
                                             __HIP_MEMORY_SCOPE_AGENT) == 0)
                        __builtin_amdgcn_s_sleep(8);
                }
                __syncthreads();
                // stage h0 tile [n, n+31] from d_out, f32->f16, transposed
                {
                    int c = tid >> 3, q = tid & 7;
                    float4 v = *(const float4*)(ob + (size_t)c * SEQ + n + 4 * q);
                    opb16[(4 * q + 0) * XST + c] = (_Float16)v.x;
                    opb16[(4 * q + 1) * XST + c] = (_Float16)v.y;
                    opb16[(4 * q + 2) * XST + c] = (_Float16)v.z;
                    opb16[(4 * q + 3) * XST + c] = (_Float16)v.w;
                }
                __syncthreads();
            }
            {
                const float4* op4 = (half == 0)
                    ? (const float4*)(opb16 + (n & 31) * XST)
                    : (const float4*)(hbuf2[n & 1]);
                float a0 = 0.f, a1 = 0.f, a2 = 0.f, a3 = 0.f;
#pragma unroll
                for (int i = 0; i < 8; ++i) {
                    H8 o; o.f4 = op4[i];
                    a0 = dot2(w[i].h2[0], o.h2[0], a0);
                    a1 = dot2(w[i].h2[1], o.h2[1], a1);
                    a2 = dot2(w[i].h2[2], o.h2[2], a2);
                    a3 = dot2(w[i].h2[3], o.h2[3], a3);
                }
                partial[tid] = (a0 + a1) + (a2 + a3);
            }
            __syncthreads();
            if (tid < 64) {
                float pi = partial[tid]       + partial[tid + 256] + bi;
                float pf = partial[tid + 64]  + partial[tid + 320] + bf;
                float pg = partial[tid + 128] + partial[tid + 384] + bg;
                float po = partial[tid + 192] + partial[tid + 448] + bo;
                float ii = sigm(pi), ff = sigm(pf), gg = tanh_(pg), oo = sigm(po);
                cst = ff * cst + ii * gg;
                float h = oo * tanh_(cst);
                hbuf2[(n + 1) & 1][tid] = (_Float16)h;
                stg[tid * 37 + (n & 31)] = h;
            }
            __syncthreads();
            if ((n & 31) == 31) {
                // overwrite d_out tile with h1
                int t0 = n - 31;
                int c = tid >> 3, q = tid & 7;
                float4 v;
                v.x = stg[c * 37 + 4 * q + 0];
                v.y = stg[c * 37 + 4 * q + 1];
                v.z = stg[c * 37 + 4 * q + 2];
                v.w = stg[c * 37 + 4 * q + 3];
                *(float4*)(ob + (size_t)c * SEQ + t0 + 4 * q) = v;
            }
        }
    }
}

extern "C" void kernel_launch(void* const* d_in, const int* in_sizes, int n_in,
                              void* d_out, int out_size, void* d_ws, size_t ws_size,
                              hipStream_t stream) {
    const float* x    = (const float*)d_in[0];
    const float* wih0 = (const float*)d_in[1];
    const float* whh0 = (const float*)d_in[2];
    const float* b0   = (const float*)d_in[3];
    const float* wih1 = (const float*)d_in[4];
    const float* whh1 = (const float*)d_in[5];
    const float* b1   = (const float*)d_in[6];
    float* out   = (float*)d_out;
    int*   flags = (int*)d_ws;           // 128 batches x 128 tiles

    zero_flags<<<64, 256, 0, stream>>>(flags, 128 * 128);
    lstm2_split_f16<<<256, 512, 0, stream>>>(x, wih0, whh0, b0, wih1, whh1, b1,
                                             out, flags);
}